// Round 1
// baseline (302.324 us; speedup 1.0000x reference)
//
#include <hip/hip_runtime.h>

// LabelizerNet: avg-pool(6,2) -> RGB->HSV -> yellow/blue mask -> per-panel max/min
// Input : states (N, 3, 84, 84) f32   (N = 4096)
// Output: labels (N, 6) f32  [yellow panels 0..2, blue panels 0..2]

#define IMG_H 84
#define IMG_W 84
#define CH_ELEMS (IMG_H * IMG_W)   // 7056
#define P_W 40                     // pooled width  ((84-6)/2+1)
#define NPIX (40 * 40)             // 1600 pooled pixels
#define THREADS 256
#define PPT 7                      // ceil(1600/256)

__global__ __launch_bounds__(THREADS)
void labelizer_kernel(const float* __restrict__ in, float* __restrict__ out) {
    __shared__ float lds[CH_ELEMS];        // one channel, 28224 B
    __shared__ unsigned panel_bits;        // 9 bits: (anyY, anyB, anyZ) x 3 panels

    const int n = blockIdx.x;
    const int tid = threadIdx.x;
    if (tid == 0) panel_bits = 0u;

    const float* img = in + (size_t)n * (3 * CH_ELEMS);
    float pooled[PPT][3];

    #pragma unroll
    for (int c = 0; c < 3; ++c) {
        __syncthreads();  // also orders panel_bits=0 before atomics; guards lds reuse
        // ---- stage channel c into LDS (coalesced float4) ----
        const float4* src = (const float4*)(img + c * CH_ELEMS);
        float4* dst = (float4*)lds;
        for (int i = tid; i < CH_ELEMS / 4; i += THREADS) dst[i] = src[i];
        __syncthreads();
        // ---- 6x6 window sums for this thread's pooled pixels ----
        #pragma unroll
        for (int k = 0; k < PPT; ++k) {
            int p = tid + k * THREADS;
            if (p < NPIX) {
                int y = p / P_W;
                int x = p - y * P_W;
                const float* base = lds + (2 * y) * IMG_W + 2 * x;  // 8B-aligned
                float rs[6];
                #pragma unroll
                for (int r = 0; r < 6; ++r) {
                    const float2* rp = (const float2*)(base + r * IMG_W);
                    float2 f0 = rp[0], f1 = rp[1], f2 = rp[2];
                    rs[r] = (f0.x + f0.y) + (f1.x + f1.y) + (f2.x + f2.y);
                }
                float tot = ((rs[0] + rs[1]) + (rs[2] + rs[3])) + (rs[4] + rs[5]);
                pooled[k][c] = tot / 36.0f;
            }
        }
    }

    // ---- HSV + classification + per-panel bit accumulation ----
    unsigned my = 0;
    #pragma unroll
    for (int k = 0; k < PPT; ++k) {
        int p = tid + k * THREADS;
        if (p < NPIX) {
            float r = pooled[k][0], g = pooled[k][1], b = pooled[k][2];
            float maxc = fmaxf(r, fmaxf(g, b));
            float minc = fminf(r, fminf(g, b));
            float delta = maxc - minc;
            float s = (maxc == 0.0f) ? 0.0f : delta / maxc;
            float v = maxc;
            float h = 0.0f;
            if (delta != 0.0f) {
                float rc = (maxc - r) / delta;
                float gc = (maxc - g) / delta;
                float bc = (maxc - b) / delta;
                float hh = (r == maxc) ? (bc - gc)
                         : ((g == maxc) ? (2.0f + rc - bc)
                                        : (4.0f + gc - rc));
                h = hh / 6.0f;           // in (-1/6, 5/6); floor-mod 1:
                if (h < 0.0f) h += 1.0f;
            }
            bool satval = (s > 0.5f) && (v > 0.5f);
            int m = 0;
            if (satval && h >= 0.1f && h <= 0.2f) m = 1;
            else if (satval && h >= 0.55f && h <= 0.7f) m = -1;

            int x = p - (p / P_W) * P_W;
            if (x < 39) {                 // col 39 excluded (40//3*3 == 39)
                int pan = x / 13;         // 0..2
                unsigned bit = (m > 0) ? 1u : (m < 0) ? 2u : 4u;
                my |= bit << (3 * pan);
            }
        }
    }

    // wave-level OR-reduce, then one shared atomic per wave
    #pragma unroll
    for (int off = 32; off > 0; off >>= 1) my |= __shfl_xor(my, off);
    if ((tid & 63) == 0 && my) atomicOr(&panel_bits, my);
    __syncthreads();

    if (tid < 6) {
        int pan = (tid < 3) ? tid : tid - 3;
        unsigned pb = panel_bits >> (3 * pan);
        bool anyY = pb & 1u;
        bool anyB = (pb >> 1) & 1u;
        bool anyZ = (pb >> 2) & 1u;
        float val;
        if (tid < 3) val = anyY ? 1.0f : (anyZ ? 0.0f : -1.0f);   // max(panel)
        else         val = anyB ? 1.0f : (anyZ ? 0.0f : -1.0f);   // -min(panel)
        out[(size_t)n * 6 + tid] = val;
    }
}

extern "C" void kernel_launch(void* const* d_in, const int* in_sizes, int n_in,
                              void* d_out, int out_size, void* d_ws, size_t ws_size,
                              hipStream_t stream) {
    const float* states = (const float*)d_in[0];
    float* out = (float*)d_out;
    int N = in_sizes[0] / (3 * CH_ELEMS);   // 4096
    labelizer_kernel<<<N, THREADS, 0, stream>>>(states, out);
}

// Round 2
// 149.963 us; speedup vs baseline: 2.0160x; 2.0160x over previous
//
#include <hip/hip_runtime.h>

// LabelizerNet: avg-pool(6,2) -> RGB->HSV -> yellow/blue mask -> per-panel max/min
// Input : states (N, 3, 84, 84) f32   (N = 4096)
// Output: labels (N, 6) f32  [yellow panels 0..2, blue panels 0..2]
//
// Round 2: no LDS staging. Thread-per-pooled-pixel with direct global stride-2
// float2 reads (lane-contiguous => fully coalesced); L1/L2 absorb the 3x
// horizontal + 3x vertical window overlap. No barriers in the hot path.

#define IMG_H 84
#define IMG_W 84
#define CH_ELEMS (IMG_H * IMG_W)   // 7056
#define P_W 40                     // pooled width  ((84-6)/2+1)
#define NPIX (40 * 40)             // 1600 pooled pixels
#define THREADS 256
#define PPT 7                      // ceil(1600/256)

__global__ __launch_bounds__(THREADS, 4)
void labelizer_kernel(const float* __restrict__ in, float* __restrict__ out) {
    __shared__ unsigned panel_bits;        // 9 bits: (anyY, anyB, anyZ) x 3 panels

    const int n = blockIdx.x;
    const int tid = threadIdx.x;
    if (tid == 0) panel_bits = 0u;
    __syncthreads();

    const float* img = in + (size_t)n * (3 * CH_ELEMS);

    unsigned my = 0;
    for (int k = 0; k < PPT; ++k) {
        int p = tid + k * THREADS;
        if (p < NPIX) {
            int y = p / P_W;
            int x = p - y * P_W;
            const float* base = img + (2 * y) * IMG_W + 2 * x;  // 8B-aligned

            float col[3];
            #pragma unroll
            for (int c = 0; c < 3; ++c) {
                const float* cb = base + c * CH_ELEMS;
                float rs[6];
                #pragma unroll
                for (int r = 0; r < 6; ++r) {
                    const float2* rp = (const float2*)(cb + r * IMG_W);
                    float2 f0 = rp[0], f1 = rp[1], f2 = rp[2];
                    rs[r] = (f0.x + f0.y) + (f1.x + f1.y) + (f2.x + f2.y);
                }
                float tot = ((rs[0] + rs[1]) + (rs[2] + rs[3])) + (rs[4] + rs[5]);
                col[c] = tot / 36.0f;
            }

            float r = col[0], g = col[1], b = col[2];
            float maxc = fmaxf(r, fmaxf(g, b));
            float minc = fminf(r, fminf(g, b));
            float delta = maxc - minc;
            float s = (maxc == 0.0f) ? 0.0f : delta / maxc;
            float v = maxc;
            float h = 0.0f;
            if (delta != 0.0f) {
                float rc = (maxc - r) / delta;
                float gc = (maxc - g) / delta;
                float bc = (maxc - b) / delta;
                float hh = (r == maxc) ? (bc - gc)
                         : ((g == maxc) ? (2.0f + rc - bc)
                                        : (4.0f + gc - rc));
                h = hh / 6.0f;           // in (-1/6, 5/6); floor-mod 1:
                if (h < 0.0f) h += 1.0f;
            }
            bool satval = (s > 0.5f) && (v > 0.5f);
            int m = 0;
            if (satval && h >= 0.1f && h <= 0.2f) m = 1;
            else if (satval && h >= 0.55f && h <= 0.7f) m = -1;

            if (x < 39) {                 // col 39 excluded (40//3*3 == 39)
                int pan = x / 13;         // 0..2
                unsigned bit = (m > 0) ? 1u : (m < 0) ? 2u : 4u;
                my |= bit << (3 * pan);
            }
        }
    }

    // wave-level OR-reduce, then one shared atomic per wave
    #pragma unroll
    for (int off = 32; off > 0; off >>= 1) my |= __shfl_xor(my, off);
    if ((tid & 63) == 0 && my) atomicOr(&panel_bits, my);
    __syncthreads();

    if (tid < 6) {
        int pan = (tid < 3) ? tid : tid - 3;
        unsigned pb = panel_bits >> (3 * pan);
        bool anyY = pb & 1u;
        bool anyB = (pb >> 1) & 1u;
        bool anyZ = (pb >> 2) & 1u;
        float val;
        if (tid < 3) val = anyY ? 1.0f : (anyZ ? 0.0f : -1.0f);   // max(panel)
        else         val = anyB ? 1.0f : (anyZ ? 0.0f : -1.0f);   // -min(panel)
        out[(size_t)n * 6 + tid] = val;
    }
}

extern "C" void kernel_launch(void* const* d_in, const int* in_sizes, int n_in,
                              void* d_out, int out_size, void* d_ws, size_t ws_size,
                              hipStream_t stream) {
    const float* states = (const float*)d_in[0];
    float* out = (float*)d_out;
    int N = in_sizes[0] / (3 * CH_ELEMS);   // 4096
    labelizer_kernel<<<N, THREADS, 0, stream>>>(states, out);
}

// Round 3
// 111.255 us; speedup vs baseline: 2.7174x; 1.3479x over previous
//
#include <hip/hip_runtime.h>

// LabelizerNet: avg-pool(6,2) -> RGB->HSV -> yellow/blue mask -> per-panel max/min
// Input : states (N, 3, 84, 84) f32   (N = 4096)
// Output: labels (N, 6) f32  [yellow panels 0..2, blue panels 0..2]
//
// Round 3: pooled-pixel PAIRS per thread. The two windows' union is 8 contiguous
// columns = 2 float4 loads/row (vs 6 float2), 3x fewer load instructions, 1.5x
// fewer bytes. Pair-sum reuse keeps float grouping bit-identical to round 2.

#define IMG_H 84
#define IMG_W 84
#define CH_ELEMS (IMG_H * IMG_W)   // 7056
#define P_W 40                     // pooled width  ((84-6)/2+1)
#define PAIRS_W 20                 // pixel pairs per pooled row
#define NPAIRS (40 * PAIRS_W)      // 800 pairs per image
#define THREADS 256
#define PPT 4                      // ceil(800/256)

__global__ __launch_bounds__(THREADS, 4)
void labelizer_kernel(const float* __restrict__ in, float* __restrict__ out) {
    __shared__ unsigned panel_bits;        // 9 bits: (anyY, anyB, anyZ) x 3 panels

    const int n = blockIdx.x;
    const int tid = threadIdx.x;
    if (tid == 0) panel_bits = 0u;
    __syncthreads();

    const float* img = in + (size_t)n * (3 * CH_ELEMS);

    unsigned my = 0;
    #pragma unroll
    for (int k = 0; k < PPT; ++k) {
        int pp = tid + k * THREADS;
        if (pp < NPAIRS) {
            int y = pp / PAIRS_W;
            int xp = pp - y * PAIRS_W;              // pair index 0..19
            const float* base = img + (2 * y) * IMG_W + 4 * xp;  // 16B-aligned

            float p0[3], p1[3];
            #pragma unroll
            for (int c = 0; c < 3; ++c) {
                const float* cb = base + c * CH_ELEMS;
                float rs0[6], rs1[6];
                #pragma unroll
                for (int r = 0; r < 6; ++r) {
                    const float4* rp = (const float4*)(cb + r * IMG_W);
                    float4 q0 = rp[0], q1 = rp[1];
                    float a01 = q0.x + q0.y;
                    float a23 = q0.z + q0.w;
                    float a45 = q1.x + q1.y;
                    float a67 = q1.z + q1.w;
                    rs0[r] = (a01 + a23) + a45;     // window at x = 2*xp
                    rs1[r] = (a23 + a45) + a67;     // window at x = 2*xp+1
                }
                float t0 = ((rs0[0] + rs0[1]) + (rs0[2] + rs0[3])) + (rs0[4] + rs0[5]);
                float t1 = ((rs1[0] + rs1[1]) + (rs1[2] + rs1[3])) + (rs1[4] + rs1[5]);
                p0[c] = t0 / 36.0f;
                p1[c] = t1 / 36.0f;
            }

            #pragma unroll
            for (int e = 0; e < 2; ++e) {
                float r = (e == 0) ? p0[0] : p1[0];
                float g = (e == 0) ? p0[1] : p1[1];
                float b = (e == 0) ? p0[2] : p1[2];
                int x = 2 * xp + e;

                float maxc = fmaxf(r, fmaxf(g, b));
                float minc = fminf(r, fminf(g, b));
                float delta = maxc - minc;
                float s = (maxc == 0.0f) ? 0.0f : delta / maxc;
                float v = maxc;
                float h = 0.0f;
                if (delta != 0.0f) {
                    float rc = (maxc - r) / delta;
                    float gc = (maxc - g) / delta;
                    float bc = (maxc - b) / delta;
                    float hh = (r == maxc) ? (bc - gc)
                             : ((g == maxc) ? (2.0f + rc - bc)
                                            : (4.0f + gc - rc));
                    h = hh / 6.0f;           // in (-1/6, 5/6); floor-mod 1:
                    if (h < 0.0f) h += 1.0f;
                }
                bool satval = (s > 0.5f) && (v > 0.5f);
                int m = 0;
                if (satval && h >= 0.1f && h <= 0.2f) m = 1;
                else if (satval && h >= 0.55f && h <= 0.7f) m = -1;

                if (x < 39) {                 // col 39 excluded (40//3*3 == 39)
                    int pan = x / 13;         // 0..2
                    unsigned bit = (m > 0) ? 1u : (m < 0) ? 2u : 4u;
                    my |= bit << (3 * pan);
                }
            }
        }
    }

    // wave-level OR-reduce, then one shared atomic per wave
    #pragma unroll
    for (int off = 32; off > 0; off >>= 1) my |= __shfl_xor(my, off);
    if ((tid & 63) == 0 && my) atomicOr(&panel_bits, my);
    __syncthreads();

    if (tid < 6) {
        int pan = (tid < 3) ? tid : tid - 3;
        unsigned pb = panel_bits >> (3 * pan);
        bool anyY = pb & 1u;
        bool anyB = (pb >> 1) & 1u;
        bool anyZ = (pb >> 2) & 1u;
        float val;
        if (tid < 3) val = anyY ? 1.0f : (anyZ ? 0.0f : -1.0f);   // max(panel)
        else         val = anyB ? 1.0f : (anyZ ? 0.0f : -1.0f);   // -min(panel)
        out[(size_t)n * 6 + tid] = val;
    }
}

extern "C" void kernel_launch(void* const* d_in, const int* in_sizes, int n_in,
                              void* d_out, int out_size, void* d_ws, size_t ws_size,
                              hipStream_t stream) {
    const float* states = (const float*)d_in[0];
    float* out = (float*)d_out;
    int N = in_sizes[0] / (3 * CH_ELEMS);   // 4096
    labelizer_kernel<<<N, THREADS, 0, stream>>>(states, out);
}